// Round 2
// baseline (916.992 us; speedup 1.0000x reference)
//
#include <hip/hip_runtime.h>

typedef unsigned short u16;
typedef unsigned int u32;
typedef __attribute__((ext_vector_type(8))) short bf16x8;
typedef __attribute__((ext_vector_type(4))) float f32x4;

__device__ inline u16 f2bf(float x) {
  u32 u = __float_as_uint(x);
  u32 r = (u + 0x7FFFu + ((u >> 16) & 1u)) >> 16;
  return (u16)r;
}
__device__ inline float bf2f(u16 h) { return __uint_as_float(((u32)h) << 16); }
__device__ inline float sigm(float x) { return 1.f / (1.f + __expf(-x)); }
__device__ inline float tanh_s(float x) {
  float ax = fabsf(x);
  float e = __expf(2.f * ax);
  float t = 1.f - 2.f / (e + 1.f);
  return copysignf(t, x);
}

// ---------------- weight convert helpers ----------------
__global__ void cvt_f32_bf16(const float* __restrict__ s, u16* __restrict__ d, int n) {
  int i = (blockIdx.x * 256 + threadIdx.x) * 4;
  if (i < n) {
    float4 f = *(const float4*)&s[i];
    u32 lo = (u32)f2bf(f.x) | ((u32)f2bf(f.y) << 16);
    u32 hi = (u32)f2bf(f.z) | ((u32)f2bf(f.w) << 16);
    uint2 v; v.x = lo; v.y = hi;
    *(uint2*)&d[i] = v;
  }
}

__global__ void bias_add(const float* __restrict__ a, const float* __restrict__ b,
                         float* __restrict__ d, int n) {
  int i = blockIdx.x * 256 + threadIdx.x;
  if (i < n) d[i] = a[i] + b[i];
}

// ---------------- generic C = A * B^T GEMM (bf16 MFMA) ----------------
// A: [M,K] (f32 if A_F32 else bf16), B: [N,K] bf16 row-major, C: [M,N]
// 128x128 tile, BK=64, 4 waves (2x2), per-wave 64x64 via 4x4 frags of 16x16x32.
template <int A_F32, int OUT_BF16>
__global__ __launch_bounds__(256) void gemm_bt(
    const void* __restrict__ Ap, const u16* __restrict__ Bp,
    const float* __restrict__ bias, void* __restrict__ Cp,
    int K, int lda, int ldb, int ldc) {
  __shared__ u16 Alds[128 * 64];
  __shared__ u16 Blds[128 * 64];
  const int tid = threadIdx.x;
  const int lane = tid & 63;
  const int w = tid >> 6;
  const int wm = w >> 1, wn = w & 1;
  const int m0 = blockIdx.x * 128, n0 = blockIdx.y * 128;
  const int r = lane & 15, kb = lane >> 4;

  f32x4 acc[4][4];
#pragma unroll
  for (int m = 0; m < 4; ++m)
#pragma unroll
    for (int n = 0; n < 4; ++n) acc[m][n] = (f32x4)0.f;

  for (int k0 = 0; k0 < K; k0 += 64) {
    // stage A tile (128x64 bf16) and B tile (128x64 bf16)
#pragma unroll
    for (int p = 0; p < 4; ++p) {
      int ch = p * 256 + tid;
      int row = ch >> 3;
      int col = (ch & 7) * 8;
      if (A_F32) {
        const float* s = (const float*)Ap + (size_t)(m0 + row) * lda + k0 + col;
        float4 f0 = *(const float4*)s;
        float4 f1 = *(const float4*)(s + 4);
        uint4 v;
        v.x = (u32)f2bf(f0.x) | ((u32)f2bf(f0.y) << 16);
        v.y = (u32)f2bf(f0.z) | ((u32)f2bf(f0.w) << 16);
        v.z = (u32)f2bf(f1.x) | ((u32)f2bf(f1.y) << 16);
        v.w = (u32)f2bf(f1.z) | ((u32)f2bf(f1.w) << 16);
        *(uint4*)&Alds[row * 64 + col] = v;
      } else {
        uint4 v = *(const uint4*)((const u16*)Ap + (size_t)(m0 + row) * lda + k0 + col);
        *(uint4*)&Alds[row * 64 + col] = v;
      }
      uint4 vb = *(const uint4*)(Bp + (size_t)(n0 + row) * ldb + k0 + col);
      *(uint4*)&Blds[row * 64 + col] = vb;
    }
    __syncthreads();
#pragma unroll
    for (int ks = 0; ks < 2; ++ks) {
      int kk = ks * 32 + kb * 8;
      bf16x8 af[4], bfr[4];
#pragma unroll
      for (int m = 0; m < 4; ++m)
        af[m] = *(const bf16x8*)&Alds[(wm * 64 + m * 16 + r) * 64 + kk];
#pragma unroll
      for (int n = 0; n < 4; ++n)
        bfr[n] = *(const bf16x8*)&Blds[(wn * 64 + n * 16 + r) * 64 + kk];
#pragma unroll
      for (int m = 0; m < 4; ++m)
#pragma unroll
        for (int n = 0; n < 4; ++n)
          acc[m][n] = __builtin_amdgcn_mfma_f32_16x16x32_bf16(af[m], bfr[n], acc[m][n], 0, 0, 0);
    }
    __syncthreads();
  }

  // epilogue: D row = (lane>>4)*4 + j, col = lane&15 within each 16x16 frag
  const int r4 = kb * 4;
#pragma unroll
  for (int m = 0; m < 4; ++m) {
#pragma unroll
    for (int n = 0; n < 4; ++n) {
      int row = m0 + wm * 64 + m * 16 + r4;
      int col = n0 + wn * 64 + n * 16 + (lane & 15);
      float bv = bias[col];
#pragma unroll
      for (int j = 0; j < 4; ++j) {
        float v = acc[m][n][j] + bv;
        if (OUT_BF16)
          ((u16*)Cp)[(size_t)(row + j) * ldc + col] = f2bf(v);
        else
          ((float*)Cp)[(size_t)(row + j) * ldc + col] = v;
      }
    }
  }
}

// ---------------- one LSTM step ----------------
// grid (16,16): block = (32 batch rows) x (32 hidden cols); 4 waves = gates i,f,g,o.
// gates = xg[t] + h_{t-1} @ W_hh^T ; c = sig(f)*c + sig(i)*tanh(g); h = sig(o)*tanh(c)
__global__ __launch_bounds__(256) void lstm_step(
    const u16* __restrict__ xg,    // [B*T][2048], row = b*64+t
    const u16* __restrict__ Whh,   // [2048][512] bf16
    const u16* __restrict__ hs_r,  // [B*T][512] bf16 (reads row b*64+t-1)
    u16* __restrict__ hs_w,        // same buffer (writes row b*64+t)
    float* __restrict__ cst,       // [512][512] f32
    int t) {
  __shared__ u16 Ah[32 * 64];
  __shared__ u16 Bw[128 * 64];
  __shared__ float G[4 * 1024];
  const int tid = threadIdx.x;
  const int lane = tid & 63;
  const int g = tid >> 6;  // wave id == gate id
  const int b0 = blockIdx.x * 32, hc0 = blockIdx.y * 32;
  const int r = lane & 15, kb = lane >> 4;

  f32x4 acc[2][2];
#pragma unroll
  for (int m = 0; m < 2; ++m)
#pragma unroll
    for (int n = 0; n < 2; ++n) acc[m][n] = (f32x4)0.f;

  if (t > 0) {
    for (int k0 = 0; k0 < 512; k0 += 64) {
      {  // A: h_{t-1} tile 32x64 (rows strided by T in hs)
        int row = tid >> 3;
        int col = (tid & 7) * 8;
        uint4 v = *(const uint4*)&hs_r[((size_t)(b0 + row) * 64 + (t - 1)) * 512 + k0 + col];
        *(uint4*)&Ah[row * 64 + col] = v;
      }
#pragma unroll
      for (int p = 0; p < 4; ++p) {  // B: 4 gates x 32 rows of W_hh
        int ch = p * 256 + tid;
        int row = ch >> 3;
        int col = (ch & 7) * 8;
        int gg = row >> 5, rr = row & 31;
        uint4 v = *(const uint4*)&Whh[((size_t)gg * 512 + hc0 + rr) * 512 + k0 + col];
        *(uint4*)&Bw[row * 64 + col] = v;
      }
      __syncthreads();
#pragma unroll
      for (int ks = 0; ks < 2; ++ks) {
        int kk = ks * 32 + kb * 8;
        bf16x8 af[2], bfr[2];
#pragma unroll
        for (int m = 0; m < 2; ++m)
          af[m] = *(const bf16x8*)&Ah[(m * 16 + r) * 64 + kk];
#pragma unroll
        for (int n = 0; n < 2; ++n)
          bfr[n] = *(const bf16x8*)&Bw[(g * 32 + n * 16 + r) * 64 + kk];
#pragma unroll
        for (int m = 0; m < 2; ++m)
#pragma unroll
          for (int n = 0; n < 2; ++n)
            acc[m][n] = __builtin_amdgcn_mfma_f32_16x16x32_bf16(af[m], bfr[n], acc[m][n], 0, 0, 0);
      }
      __syncthreads();
    }
  }

  // publish this wave's gate tile to LDS
#pragma unroll
  for (int m = 0; m < 2; ++m)
#pragma unroll
    for (int n = 0; n < 2; ++n)
#pragma unroll
      for (int j = 0; j < 4; ++j)
        G[g * 1024 + ((m * 2 + n) * 4 + j) * 64 + lane] = acc[m][n][j];
  __syncthreads();

  // fused elementwise LSTM update: 1024 elements, 4 per thread
#pragma unroll
  for (int q = 0; q < 4; ++q) {
    int e = q * 256 + tid;
    int l = e & 63;
    int rr = e >> 6;
    int j = rr & 3;
    int mn = rr >> 2;
    int m = mn >> 1, n = mn & 1;
    int brow = m * 16 + (l >> 4) * 4 + j;
    int col = n * 16 + (l & 15);
    int b = b0 + brow;
    int hcol = hc0 + col;
    size_t xrow = ((size_t)b * 64 + t) * 2048;
    float vi = G[0 * 1024 + e] + bf2f(xg[xrow + 0 * 512 + hcol]);
    float vf = G[1 * 1024 + e] + bf2f(xg[xrow + 1 * 512 + hcol]);
    float vg = G[2 * 1024 + e] + bf2f(xg[xrow + 2 * 512 + hcol]);
    float vo = G[3 * 1024 + e] + bf2f(xg[xrow + 3 * 512 + hcol]);
    float ii = sigm(vi);
    float ff = sigm(vf);
    float gg = tanh_s(vg);
    float oo = sigm(vo);
    float cp = (t == 0) ? 0.f : cst[(size_t)b * 512 + hcol];
    float cn = ff * cp + ii * gg;
    float hn = oo * tanh_s(cn);
    cst[(size_t)b * 512 + hcol] = cn;
    hs_w[((size_t)b * 64 + t) * 512 + hcol] = f2bf(hn);
  }
}

// ---------------- launch ----------------
extern "C" void kernel_launch(void* const* d_in, const int* in_sizes, int n_in,
                              void* d_out, int out_size, void* d_ws, size_t ws_size,
                              hipStream_t stream) {
  (void)in_sizes; (void)n_in; (void)out_size; (void)ws_size;
  const float* msg   = (const float*)d_in[0];  // [512,64,1024]
  const float* W_emb = (const float*)d_in[1];  // [256,1024]
  const float* b_emb = (const float*)d_in[2];  // [256]
  const float* W_ih  = (const float*)d_in[3];  // [2048,256]
  const float* b_ih  = (const float*)d_in[4];  // [2048]
  const float* W_hh  = (const float*)d_in[5];  // [2048,512]
  const float* b_hh  = (const float*)d_in[6];  // [2048]
  const float* W_ag  = (const float*)d_in[7];  // [256,512]
  const float* b_ag  = (const float*)d_in[8];  // [256]
  float* out = (float*)d_out;                  // [512,64,256]

  char* p = (char*)d_ws;
  u16* Wemb_b = (u16*)p;  p += (size_t)256 * 1024 * 2;
  u16* Wih_b  = (u16*)p;  p += (size_t)2048 * 256 * 2;
  u16* Whh_b  = (u16*)p;  p += (size_t)2048 * 512 * 2;
  u16* Wag_b  = (u16*)p;  p += (size_t)256 * 512 * 2;
  float* bc   = (float*)p; p += (size_t)2048 * 4;
  p = (char*)(((size_t)p + 255) & ~(size_t)255);
  u16* emb_b = (u16*)p;   p += (size_t)32768 * 256 * 2;   // 16 MB
  u16* xg    = (u16*)p;   p += (size_t)32768 * 2048 * 2;  // 128 MB
  u16* hs    = (u16*)p;   p += (size_t)32768 * 512 * 2;   // 32 MB
  float* cst = (float*)p;                                  // 1 MB
  // total ws use ~181 MB

  // weight converts (redone every call; ws is re-poisoned by harness)
  cvt_f32_bf16<<<256, 256, 0, stream>>>(W_emb, Wemb_b, 256 * 1024);
  cvt_f32_bf16<<<512, 256, 0, stream>>>(W_ih, Wih_b, 2048 * 256);
  cvt_f32_bf16<<<1024, 256, 0, stream>>>(W_hh, Whh_b, 2048 * 512);
  cvt_f32_bf16<<<128, 256, 0, stream>>>(W_ag, Wag_b, 256 * 512);
  bias_add<<<8, 256, 0, stream>>>(b_ih, b_hh, bc, 2048);

  // emb[B*T,256] = msg[B*T,1024] @ W_emb^T + b_emb   (bf16 out)
  gemm_bt<1, 1><<<dim3(256, 2), 256, 0, stream>>>(msg, Wemb_b, b_emb, emb_b,
                                                  1024, 1024, 1024, 256);
  // xg[B*T,2048] = emb @ W_ih^T + (b_ih+b_hh)        (bf16 out)
  gemm_bt<0, 1><<<dim3(256, 16), 256, 0, stream>>>(emb_b, Wih_b, bc, xg,
                                                   256, 256, 256, 2048);
  // recurrence
  for (int t = 0; t < 64; ++t)
    lstm_step<<<dim3(16, 16), 256, 0, stream>>>(xg, Whh_b, hs, hs, cst, t);
  // out[B*T,256] = hs @ W_agent^T + b_agent          (f32 out)
  gemm_bt<0, 0><<<dim3(256, 2), 256, 0, stream>>>(hs, Wag_b, b_ag, out,
                                                  512, 512, 512, 256);
}